// Round 5
// baseline (135.590 us; speedup 1.0000x reference)
//
#include <hip/hip_runtime.h>
#include <cstddef>

#define B_   4
#define NQ_  8192
#define C_   256
#define H_   128
#define W_   128
#define HW_  (H_ * W_)
#define NH_  8
#define NP_  4
#define HD_  32

typedef __attribute__((ext_vector_type(8))) short s16x8;
typedef __attribute__((ext_vector_type(4))) float f32x4;

__device__ __forceinline__ short f2bf(float x) {
    unsigned u = __float_as_uint(x);
    unsigned r = (u + 0x7FFFu + ((u >> 16) & 1u)) >> 16;
    return (short)r;
}
__device__ __forceinline__ void gload_lds16(const void* g, void* l) {
    __builtin_amdgcn_global_load_lds(
        (const __attribute__((address_space(1))) void*)g,
        (__attribute__((address_space(3))) void*)l, 16, 0, 0);
}

// ---------------------------------------------------------------------------
// Prep: transposed bf16 weights Bt[n][k] (+ composite off|attn matrix padded
// to 128 cols, and its padded bias).
// ---------------------------------------------------------------------------
__global__ void prep_kernel(const float* __restrict__ Wv, const float* __restrict__ Wo,
                            const float* __restrict__ Woff, const float* __restrict__ Wattn,
                            const float* __restrict__ boff, const float* __restrict__ battn,
                            short* __restrict__ BtVal, short* __restrict__ BtOut,
                            short* __restrict__ BtOA, float* __restrict__ biasOA)
{
    const int b = blockIdx.x, t = threadIdx.x;   // t = k index, 0..255
    if (b < 256) {
        const int n = b;
        BtVal[(size_t)n * 256 + t] = f2bf(Wv[(size_t)t * 256 + n]);
    } else if (b < 512) {
        const int n = b - 256;
        BtOut[(size_t)n * 256 + t] = f2bf(Wo[(size_t)t * 256 + n]);
    } else {
        const int n = b - 512;   // 0..127
        float v = (n < 64) ? Woff[(size_t)t * 64 + n]
                           : (n < 96 ? Wattn[(size_t)t * 32 + (n - 64)] : 0.f);
        BtOA[(size_t)n * 256 + t] = f2bf(v);
        if (t == 0) biasOA[n] = (n < 64) ? boff[n] : (n < 96 ? battn[n - 64] : 0.f);
    }
}

// ---------------------------------------------------------------------------
// B-stationary streaming GEMM. Whole B panel (128 n x 256 k bf16 = 64 KiB)
// lives in LDS (XOR-swizzled, staged via pre-swizzled global source since
// global_load_lds writes linearly). After ONE barrier, each wave streams
// independent 16-row A strips: 8 frags global->reg (->bf16 if ADT=1), then
// per n-fragment 8 chained MFMAs and an immediate store. No further barriers;
// latency hidden by 8 waves/CU all issuing deep independent load batches.
// Swizzle: LDS[row][colbyte] = B[row][colbyte ^ ((row&7)<<4)]  (512 B rows)
//   -> 8 consecutive n-rows use 8 distinct 16B slots => conflict-free b128.
// ADT: 0 = A bf16, 1 = A f32 (converted in-reg). OM: 0 = f32 C[m*ldc+n],
// 2 = bf16 vproj-permute store. ROWS = rows per block. HALVES = N/128.
// HALVES==2 uses XCD pairing: the two n-halves of one M-chunk land on the
// same XCD so the 2nd A read hits that XCD's L2.
// ---------------------------------------------------------------------------
template<int ADT, int OM, int ROWS, int HALVES>
__global__ __launch_bounds__(256, 2)
void gemm_bstat(const void* __restrict__ Ap, const short* __restrict__ Bt0,
                const float* __restrict__ bias, void* __restrict__ Cp,
                int ldc, int nstore)
{
    __shared__ short Bs[128 * 256];   // 64 KiB
    const int tid = threadIdx.x;
    const int l = tid & 63;
    const int w = tid >> 6;

    int mch, half;
    if (HALVES == 2) {
        const int xcd = blockIdx.x & 7;
        const int lix = blockIdx.x >> 3;
        mch = xcd * 32 + (lix >> 1);      // grid 512: 32 M-chunks per XCD
        half = lix & 1;
    } else {
        mch = blockIdx.x;
        half = 0;
    }
    const int m0 = mch * ROWS;
    const int n0 = half * 128;
    const char* BtB = (const char*)(Bt0 + (size_t)half * 128 * 256);

    // ---- stage whole B panel into LDS (swizzled via pre-swizzled source) --
    {
        const int r7 = tid >> 5;                        // row & 7, per thread
        const int scol = ((tid & 31) * 16) ^ (r7 << 4); // inverse == forward (involution)
#pragma unroll
        for (int i = 0; i < 16; ++i)
            gload_lds16(BtB + (size_t)(i * 8 + r7) * 512 + scol,
                        (char*)Bs + i * 4096 + w * 1024);
    }
    __syncthreads();   // only barrier in the kernel

    const int arow_l = l & 15;        // A-row within strip / D-col within frag
    const int kb     = (l >> 4) * 8;  // k element offset within a 32-k step
    const float* Af  = (const float*)Ap;
    const short* A16 = (const short*)Ap;

    float bias_r[8];
#pragma unroll
    for (int nf = 0; nf < 8; ++nf)
        bias_r[nf] = bias[n0 + nf * 16 + arow_l];

    for (int s = w; s < ROWS / 16; s += 4) {
        const int mrow = m0 + s * 16 + arow_l;
        // ---- A fragments straight from global (deep independent loads) ----
        s16x8 a[8];
        if (ADT == 0) {
#pragma unroll
            for (int kk = 0; kk < 8; ++kk)
                a[kk] = *(const s16x8*)(A16 + (size_t)mrow * 256 + kk * 32 + kb);
        } else {
#pragma unroll
            for (int kk = 0; kk < 8; ++kk) {
                const float* ap = Af + (size_t)mrow * 256 + kk * 32 + kb;
                const float4 u0 = ((const float4*)ap)[0];
                const float4 u1 = ((const float4*)ap)[1];
                union { short s[8]; s16x8 v; } pk;
                pk.s[0]=f2bf(u0.x); pk.s[1]=f2bf(u0.y); pk.s[2]=f2bf(u0.z); pk.s[3]=f2bf(u0.w);
                pk.s[4]=f2bf(u1.x); pk.s[5]=f2bf(u1.y); pk.s[6]=f2bf(u1.z); pk.s[7]=f2bf(u1.w);
                a[kk] = pk.v;
            }
        }
        // ---- per n-fragment: 8 chained MFMAs, immediate store ----
#pragma unroll
        for (int nf = 0; nf < 8; ++nf) {
            f32x4 acc = (f32x4)0.f;
#pragma unroll
            for (int kk = 0; kk < 8; ++kk) {
                const int brow = nf * 16 + arow_l;
                const int cswz = (kk * 64 + (l >> 4) * 16) ^ ((arow_l & 7) << 4);
                const s16x8 b = *(const s16x8*)((const char*)Bs + brow * 512 + cswz);
                acc = __builtin_amdgcn_mfma_f32_16x16x32_bf16(a[kk], b, acc, 0, 0, 0);
            }
            if (nf < nstore) {
                const int n = n0 + nf * 16 + arow_l;
                const float bs = bias_r[nf];
#pragma unroll
                for (int rr = 0; rr < 4; ++rr) {
                    const int m = m0 + s * 16 + (l >> 4) * 4 + rr;
                    const float o = acc[rr] + bs;
                    if (OM == 0) {
                        ((float*)Cp)[(size_t)m * ldc + n] = o;
                    } else {
                        const int bb = m >> 14, pix = m & (HW_ - 1);
                        const int h = n >> 5, d = n & 31;
                        ((short*)Cp)[((size_t)(bb * NH_ + h) * HW_ + pix) * HD_ + d] = f2bf(o);
                    }
                }
            }
        }
    }
}

// ---------------------------------------------------------------------------
// Sampling: block = 256 threads = 2 queries. Phase 1 (tid<64): softmax +
// corner indices + pre-multiplied weights -> LDS. Phase 2: (h, d-pair) gather.
// ---------------------------------------------------------------------------
__global__ __launch_bounds__(256)
void sample_kernel(const float* __restrict__ oa,    // [B*NQ, 128] (96 used)
                   const float* __restrict__ ref,   // [B*NQ, 2]
                   const short* __restrict__ vproj, // [B*NH, HW, HD] bf16
                   short* __restrict__ samp)        // [B*NQ, 256] bf16
{
    __shared__ int4   s_idx[2][32];
    __shared__ float4 s_w[2][32];
    const int tid = threadIdx.x;
    const int q0 = blockIdx.x * 2;

    if (tid < 64) {
        const int qq = tid >> 5;
        const int hp = tid & 31;
        const int h = hp >> 2, p = hp & 3;
        const int q = q0 + qq;
        const float logit = oa[(size_t)q * 128 + 64 + h * 4 + p];
        float mx = fmaxf(logit, __shfl_xor(logit, 1));
        mx = fmaxf(mx, __shfl_xor(mx, 2));
        float e = __expf(logit - mx);
        float s = e + __shfl_xor(e, 1);
        s += __shfl_xor(s, 2);
        const float aw = e / s;

        const float ox = oa[(size_t)q * 128 + h * 8 + p * 2 + 0] * (0.1f / (float)W_);
        const float oy = oa[(size_t)q * 128 + h * 8 + p * 2 + 1] * (0.1f / (float)H_);
        const float lx = fminf(fmaxf(ref[(size_t)q * 2 + 0] + ox, 0.f), 1.f);
        const float ly = fminf(fmaxf(ref[(size_t)q * 2 + 1] + oy, 0.f), 1.f);
        const float gx = fminf(fmaxf(lx * (float)W_ - 0.5f, 0.f), (float)(W_ - 1));
        const float gy = fminf(fmaxf(ly * (float)H_ - 0.5f, 0.f), (float)(H_ - 1));
        const float x0f = floorf(gx), y0f = floorf(gy);
        const float fx = gx - x0f, fy = gy - y0f;
        const int x0 = (int)x0f, y0 = (int)y0f;
        const int x1 = min(x0 + 1, W_ - 1), y1 = min(y0 + 1, H_ - 1);
        s_idx[qq][hp] = make_int4((y0 * W_ + x0) * HD_, (y0 * W_ + x1) * HD_,
                                  (y1 * W_ + x0) * HD_, (y1 * W_ + x1) * HD_);
        const float gx1 = 1.f - fx, gy1 = 1.f - fy;
        s_w[qq][hp] = make_float4(aw * gx1 * gy1, aw * fx * gy1,
                                  aw * gx1 * fy,  aw * fx * fy);
    }
    __syncthreads();

    const int qq = tid >> 7;
    const int t = tid & 127;
    const int h = t >> 4;
    const int d0 = (t & 15) * 2;
    const int q = q0 + qq;
    const int b = q >> 13;
    const short* vh = vproj + (size_t)(b * NH_ + h) * (HW_ * HD_) + d0;

    float a0 = 0.f, a1 = 0.f;
#pragma unroll
    for (int p = 0; p < 4; ++p) {
        const int4   ii = s_idx[qq][h * 4 + p];
        const float4 ww = s_w[qq][h * 4 + p];
        unsigned v;
        v = *(const unsigned*)&vh[ii.x];
        a0 = fmaf(ww.x, __uint_as_float(v << 16), a0);
        a1 = fmaf(ww.x, __uint_as_float(v & 0xFFFF0000u), a1);
        v = *(const unsigned*)&vh[ii.y];
        a0 = fmaf(ww.y, __uint_as_float(v << 16), a0);
        a1 = fmaf(ww.y, __uint_as_float(v & 0xFFFF0000u), a1);
        v = *(const unsigned*)&vh[ii.z];
        a0 = fmaf(ww.z, __uint_as_float(v << 16), a0);
        a1 = fmaf(ww.z, __uint_as_float(v & 0xFFFF0000u), a1);
        v = *(const unsigned*)&vh[ii.w];
        a0 = fmaf(ww.w, __uint_as_float(v << 16), a0);
        a1 = fmaf(ww.w, __uint_as_float(v & 0xFFFF0000u), a1);
    }
    const unsigned lo = (unsigned)(unsigned short)f2bf(a0);
    const unsigned hi = (unsigned)(unsigned short)f2bf(a1);
    ((unsigned*)samp)[((size_t)q * 256 + h * HD_ + d0) >> 1] = lo | (hi << 16);
}

// ---------------------------------------------------------------------------
extern "C" void kernel_launch(void* const* d_in, const int* in_sizes, int n_in,
                              void* d_out, int out_size, void* d_ws, size_t ws_size,
                              hipStream_t stream)
{
    const float* query  = (const float*)d_in[0];
    const float* refpt  = (const float*)d_in[1];
    const float* value  = (const float*)d_in[2];
    const float* W_off  = (const float*)d_in[3];
    const float* b_off  = (const float*)d_in[4];
    const float* W_attn = (const float*)d_in[5];
    const float* b_attn = (const float*)d_in[6];
    const float* W_val  = (const float*)d_in[7];
    const float* b_val  = (const float*)d_in[8];
    const float* W_out  = (const float*)d_in[9];
    const float* b_out  = (const float*)d_in[10];
    float* out = (float*)d_out;

    char* ws = (char*)d_ws;
    short* vproj  = (short*)ws;                                   // 32 MiB bf16
    short* samp   = (short*)(ws + (size_t)32 * 1024 * 1024);      // 16 MiB bf16
    float* oa     = (float*)(ws + (size_t)48 * 1024 * 1024);      // 16 MiB f32 [32768][128]
    short* BtVal  = (short*)(ws + (size_t)64 * 1024 * 1024);      // 128 KiB
    short* BtOut  = BtVal + 256 * 256;                            // 128 KiB
    short* BtOA   = BtOut + 256 * 256;                            // 64 KiB
    float* biasOA = (float*)(BtOA + 128 * 256);                   // 512 B

    prep_kernel<<<640, 256, 0, stream>>>(W_val, W_out, W_off, W_attn,
                                         b_off, b_attn, BtVal, BtOut, BtOA, biasOA);

    // K1: vproj = permute(value @ W_val + b_val), bf16 out.  512 blocks,
    // 256 rows each, 2 n-halves XCD-paired.
    gemm_bstat<1, 2, 256, 2><<<512, 256, 0, stream>>>(
        value, BtVal, b_val, vproj, 0, 8);

    // K2a: oa = query @ [W_off | W_attn | 0] + bias, f32, ldc=128, cols<96.
    gemm_bstat<1, 0, 64, 1><<<512, 256, 0, stream>>>(
        query, BtOA, biasOA, oa, 128, 6);

    // K2b: bilinear deformable sampling -> samp (bf16)
    sample_kernel<<<(B_ * NQ_) / 2, 256, 0, stream>>>(oa, refpt, vproj, samp);

    // K3: out = samp @ W_out + b_out, f32.  512 blocks, 128 rows, 2 halves.
    gemm_bstat<0, 0, 128, 2><<<512, 256, 0, stream>>>(
        samp, BtOut, b_out, out, 256, 8);
}

// Round 6
// 79.842 us; speedup vs baseline: 1.6982x; 1.6982x over previous
//
#include <hip/hip_runtime.h>
#include <cstddef>

#define B_   4
#define NQ_  8192
#define C_   256
#define H_   128
#define W_   128
#define HW_  (H_ * W_)
#define NH_  8
#define NP_  4
#define HD_  32

typedef __attribute__((ext_vector_type(8))) short s16x8;
typedef __attribute__((ext_vector_type(4))) float f32x4;

__device__ __forceinline__ short f2bf(float x) {
    unsigned u = __float_as_uint(x);
    unsigned r = (u + 0x7FFFu + ((u >> 16) & 1u)) >> 16;
    return (short)r;
}
__device__ __forceinline__ unsigned cvt_pk_bf16(float lo, float hi) {
    unsigned r;
    asm("v_cvt_pk_bf16_f32 %0, %1, %2" : "=v"(r) : "v"(lo), "v"(hi));
    return r;
}
__device__ __forceinline__ void gload_lds16(const void* g, void* l) {
    __builtin_amdgcn_global_load_lds(
        (const __attribute__((address_space(1))) void*)g,
        (__attribute__((address_space(3))) void*)l, 16, 0, 0);
}

// ---------------------------------------------------------------------------
// Prep: transposed bf16 weights Bt[n][k] (+ composite off|attn matrix padded
// to 128 cols, and its padded bias).
// ---------------------------------------------------------------------------
__global__ void prep_kernel(const float* __restrict__ Wv, const float* __restrict__ Wo,
                            const float* __restrict__ Woff, const float* __restrict__ Wattn,
                            const float* __restrict__ boff, const float* __restrict__ battn,
                            short* __restrict__ BtVal, short* __restrict__ BtOut,
                            short* __restrict__ BtOA, float* __restrict__ biasOA)
{
    const int b = blockIdx.x, t = threadIdx.x;   // t = k index, 0..255
    if (b < 256) {
        const int n = b;
        BtVal[(size_t)n * 256 + t] = f2bf(Wv[(size_t)t * 256 + n]);
    } else if (b < 512) {
        const int n = b - 256;
        BtOut[(size_t)n * 256 + t] = f2bf(Wo[(size_t)t * 256 + n]);
    } else {
        const int n = b - 512;   // 0..127
        float v = (n < 64) ? Woff[(size_t)t * 64 + n]
                           : (n < 96 ? Wattn[(size_t)t * 32 + (n - 64)] : 0.f);
        BtOA[(size_t)n * 256 + t] = f2bf(v);
        if (t == 0) biasOA[n] = (n < 64) ? boff[n] : (n < 96 ? battn[n - 64] : 0.f);
    }
}

// ---------------------------------------------------------------------------
// 2-phase double-buffered bf16 MFMA GEMM body, K=256 (8 steps of BK=32).
// 128x128 tile, 4 waves (2x2 of 64x64), mfma_f32_16x16x32_bf16.
// ALL staging via global_load_lds (no register round-trip -> no mid-step
// vmcnt(0) drain; the only drain is inside __syncthreads, R4-K3-proven).
// ADT 0: A bf16 [M][256], linear LDS rows of 64 B (8-way ds conflicts, OK).
// ADT 1: A f32  [M][256], staged RAW into LDS with XOR-swizzled GLOBAL
//   source (rule #21: gload_lds dest is linear; involution seg^=(row&7)).
//   LDS rows 128 B; swizzle makes frag reads ~2-way (free). fp32->bf16 at
//   fragment read via v_cvt_pk_bf16_f32 (RTNE).
// omode 0: f32 C[m*ldc+n]; omode 2: bf16 vproj-permute store.
// ---------------------------------------------------------------------------
template<int ADT>
__device__ __forceinline__ void gemm_body(
    const void* __restrict__ Ap, const short* __restrict__ Bt,
    const float* __restrict__ bias, void* __restrict__ Cp,
    int ldc, int omode, int m0, int n0, char* AsRaw, short* Bs)
{
    constexpr int ABYTES = (ADT == 1) ? 16384 : 8192;   // per A buffer
    const int tid = threadIdx.x;
    const int l = tid & 63;
    const int w = tid >> 6;
    const int wm = w >> 1, wn = w & 1;

    f32x4 acc[4][4];
#pragma unroll
    for (int i = 0; i < 4; ++i)
#pragma unroll
        for (int j = 0; j < 4; ++j) acc[i][j] = (f32x4)0.f;

    const int frag_r = l & 15;
    const int kslot  = (l >> 4) * 8;   // bf16 elems
    const float* Af  = (const float*)Ap;
    const short* A16 = (const short*)Ap;

#define STAGE_B(k0, buf)                                                      \
    _Pragma("unroll")                                                         \
    for (int r = 0; r < 2; ++r) {                                             \
        const int i = r * 256 + tid;                                          \
        gload_lds16(&Bt[(size_t)(n0 + (i >> 2)) * 256 + (k0) + (i & 3) * 8],  \
                    (char*)Bs + (buf) * 8192 + r * 4096 + w * 1024);          \
    }
#define STAGE_A(k0, buf)                                                      \
    if (ADT == 0) {                                                           \
        _Pragma("unroll")                                                     \
        for (int r = 0; r < 2; ++r) {                                         \
            const int i = r * 256 + tid;                                      \
            gload_lds16(&A16[(size_t)(m0 + (i >> 2)) * 256 + (k0) + (i & 3) * 8], \
                        AsRaw + (buf) * ABYTES + r * 4096 + w * 1024);        \
        }                                                                     \
    } else {                                                                  \
        _Pragma("unroll")                                                     \
        for (int r = 0; r < 4; ++r) {                                         \
            const int i = r * 256 + tid;                                      \
            const int row = i >> 3, s = i & 7;                                \
            const int colf = (s * 4) ^ ((row & 7) << 2);   /* fp32 elems */   \
            gload_lds16(&Af[(size_t)(m0 + row) * 256 + (k0) + colf],          \
                        AsRaw + (buf) * ABYTES + r * 4096 + w * 1024);        \
        }                                                                     \
    }

    // ---- prologue: fill buffer 0 ----
    STAGE_B(0, 0);
    STAGE_A(0, 0);
    __syncthreads();

#pragma unroll
    for (int k = 0; k < 8; ++k) {
        const int cur = k & 1, nxt = cur ^ 1;
        if (k < 7) {                       // prefetch next step (pure gload_lds)
            STAGE_B((k + 1) * 32, nxt);
            STAGE_A((k + 1) * 32, nxt);
        }
        // ---- fragments from current buffers ----
        s16x8 a[4], b[4];
#pragma unroll
        for (int mf = 0; mf < 4; ++mf) {
            const int row = wm * 64 + mf * 16 + frag_r;
            if (ADT == 0) {
                a[mf] = *(const s16x8*)(AsRaw + cur * ABYTES + row * 64 + kslot * 2);
            } else {
                const int g0 = (l >> 4) * 2;
                const char* base = AsRaw + cur * ABYTES + row * 128;
                const float4 q0 = *(const float4*)(base + ((g0 * 16)       ^ ((row & 7) << 4)));
                const float4 q1 = *(const float4*)(base + (((g0 + 1) * 16) ^ ((row & 7) << 4)));
                union { unsigned u[4]; s16x8 v; } pk;
                pk.u[0] = cvt_pk_bf16(q0.x, q0.y);
                pk.u[1] = cvt_pk_bf16(q0.z, q0.w);
                pk.u[2] = cvt_pk_bf16(q1.x, q1.y);
                pk.u[3] = cvt_pk_bf16(q1.z, q1.w);
                a[mf] = pk.v;
            }
        }
#pragma unroll
        for (int nf = 0; nf < 4; ++nf)
            b[nf] = *(const s16x8*)&Bs[cur * 4096 + (wn * 64 + nf * 16 + frag_r) * 32 + kslot];
#pragma unroll
        for (int mf = 0; mf < 4; ++mf)
#pragma unroll
            for (int nf = 0; nf < 4; ++nf)
                acc[mf][nf] = __builtin_amdgcn_mfma_f32_16x16x32_bf16(
                    a[mf], b[nf], acc[mf][nf], 0, 0, 0);
        if (k < 7) __syncthreads();        // single drain+barrier per step
    }
#undef STAGE_B
#undef STAGE_A

    // ---- epilogue: C frag layout col=lane&15, row=(lane>>4)*4+reg ----
    const int col_local = wn * 64 + (l & 15);
    const int rbase = wm * 64 + (l >> 4) * 4;
    if (omode == 0) {
#pragma unroll
        for (int nf = 0; nf < 4; ++nf) {
            const int n = n0 + col_local + nf * 16;
            const float bs = bias[n];
#pragma unroll
            for (int mf = 0; mf < 4; ++mf) {
                const f32x4 v = acc[mf][nf];
#pragma unroll
                for (int rr = 0; rr < 4; ++rr)
                    ((float*)Cp)[(size_t)(m0 + rbase + mf * 16 + rr) * ldc + n] = v[rr] + bs;
            }
        }
    } else {
#pragma unroll
        for (int nf = 0; nf < 4; ++nf) {
            const int n = n0 + col_local + nf * 16;
            const float bs = bias[n];
            const int h = n >> 5, d = n & 31;
#pragma unroll
            for (int mf = 0; mf < 4; ++mf) {
                const f32x4 v = acc[mf][nf];
#pragma unroll
                for (int rr = 0; rr < 4; ++rr) {
                    const int m = m0 + rbase + mf * 16 + rr;
                    const int bb = m >> 14, pix = m & (HW_ - 1);
                    ((short*)Cp)[((size_t)(bb * NH_ + h) * HW_ + pix) * HD_ + d] = f2bf(v[rr] + bs);
                }
            }
        }
    }
}

// ---------------------------------------------------------------------------
// Merged K1 + K2a: blocks 0..1023 -> vproj GEMM; 1024..1279 -> off/attn GEMM.
// LDS: A fp32 dbuf 32 KiB + B dbuf 16 KiB = 48 KiB -> 3 blocks/CU.
// ---------------------------------------------------------------------------
__global__ __launch_bounds__(256, 3)
void gemm_k1k2a(const float* __restrict__ value, const short* __restrict__ BtVal,
                const float* __restrict__ b_val, short* __restrict__ vproj,
                const float* __restrict__ query, const short* __restrict__ BtOA,
                const float* __restrict__ biasOA, float* __restrict__ oa)
{
    __shared__ char  AsRaw[2 * 16384];
    __shared__ short Bs[2 * 4096];
    const int bid = blockIdx.x;
    if (bid < 1024) {
        gemm_body<1>(value, BtVal, b_val, vproj, 0, 2,
                     (bid >> 1) * 128, (bid & 1) * 128, AsRaw, Bs);
    } else {
        gemm_body<1>(query, BtOA, biasOA, oa, 128, 0,
                     (bid - 1024) * 128, 0, AsRaw, Bs);
    }
}

// ---------------------------------------------------------------------------
// K3: out = samp @ W_out + b_out (A bf16, R4-proven roofline path)
// ---------------------------------------------------------------------------
__global__ __launch_bounds__(256, 4)
void gemm_k3(const short* __restrict__ samp, const short* __restrict__ BtOut,
             const float* __restrict__ b_out, float* __restrict__ out)
{
    __shared__ char  AsRaw[2 * 8192];
    __shared__ short Bs[2 * 4096];
    gemm_body<0>(samp, BtOut, b_out, out, 256, 0,
                 (blockIdx.x >> 1) * 128, (blockIdx.x & 1) * 128, AsRaw, Bs);
}

// ---------------------------------------------------------------------------
// Sampling: block = 256 threads = 2 queries. Phase 1 (tid<64): softmax +
// corner indices + pre-multiplied weights -> LDS. Phase 2: (h, d-pair) gather.
// ---------------------------------------------------------------------------
__global__ __launch_bounds__(256)
void sample_kernel(const float* __restrict__ oa,    // [B*NQ, 128] (96 used)
                   const float* __restrict__ ref,   // [B*NQ, 2]
                   const short* __restrict__ vproj, // [B*NH, HW, HD] bf16
                   short* __restrict__ samp)        // [B*NQ, 256] bf16
{
    __shared__ int4   s_idx[2][32];
    __shared__ float4 s_w[2][32];
    const int tid = threadIdx.x;
    const int q0 = blockIdx.x * 2;

    if (tid < 64) {
        const int qq = tid >> 5;
        const int hp = tid & 31;
        const int h = hp >> 2, p = hp & 3;
        const int q = q0 + qq;
        const float logit = oa[(size_t)q * 128 + 64 + h * 4 + p];
        float mx = fmaxf(logit, __shfl_xor(logit, 1));
        mx = fmaxf(mx, __shfl_xor(mx, 2));
        float e = __expf(logit - mx);
        float s = e + __shfl_xor(e, 1);
        s += __shfl_xor(s, 2);
        const float aw = e / s;

        const float ox = oa[(size_t)q * 128 + h * 8 + p * 2 + 0] * (0.1f / (float)W_);
        const float oy = oa[(size_t)q * 128 + h * 8 + p * 2 + 1] * (0.1f / (float)H_);
        const float lx = fminf(fmaxf(ref[(size_t)q * 2 + 0] + ox, 0.f), 1.f);
        const float ly = fminf(fmaxf(ref[(size_t)q * 2 + 1] + oy, 0.f), 1.f);
        const float gx = fminf(fmaxf(lx * (float)W_ - 0.5f, 0.f), (float)(W_ - 1));
        const float gy = fminf(fmaxf(ly * (float)H_ - 0.5f, 0.f), (float)(H_ - 1));
        const float x0f = floorf(gx), y0f = floorf(gy);
        const float fx = gx - x0f, fy = gy - y0f;
        const int x0 = (int)x0f, y0 = (int)y0f;
        const int x1 = min(x0 + 1, W_ - 1), y1 = min(y0 + 1, H_ - 1);
        s_idx[qq][hp] = make_int4((y0 * W_ + x0) * HD_, (y0 * W_ + x1) * HD_,
                                  (y1 * W_ + x0) * HD_, (y1 * W_ + x1) * HD_);
        const float gx1 = 1.f - fx, gy1 = 1.f - fy;
        s_w[qq][hp] = make_float4(aw * gx1 * gy1, aw * fx * gy1,
                                  aw * gx1 * fy,  aw * fx * fy);
    }
    __syncthreads();

    const int qq = tid >> 7;
    const int t = tid & 127;
    const int h = t >> 4;
    const int d0 = (t & 15) * 2;
    const int q = q0 + qq;
    const int b = q >> 13;
    const short* vh = vproj + (size_t)(b * NH_ + h) * (HW_ * HD_) + d0;

    float a0 = 0.f, a1 = 0.f;
#pragma unroll
    for (int p = 0; p < 4; ++p) {
        const int4   ii = s_idx[qq][h * 4 + p];
        const float4 ww = s_w[qq][h * 4 + p];
        unsigned v;
        v = *(const unsigned*)&vh[ii.x];
        a0 = fmaf(ww.x, __uint_as_float(v << 16), a0);
        a1 = fmaf(ww.x, __uint_as_float(v & 0xFFFF0000u), a1);
        v = *(const unsigned*)&vh[ii.y];
        a0 = fmaf(ww.y, __uint_as_float(v << 16), a0);
        a1 = fmaf(ww.y, __uint_as_float(v & 0xFFFF0000u), a1);
        v = *(const unsigned*)&vh[ii.z];
        a0 = fmaf(ww.z, __uint_as_float(v << 16), a0);
        a1 = fmaf(ww.z, __uint_as_float(v & 0xFFFF0000u), a1);
        v = *(const unsigned*)&vh[ii.w];
        a0 = fmaf(ww.w, __uint_as_float(v << 16), a0);
        a1 = fmaf(ww.w, __uint_as_float(v & 0xFFFF0000u), a1);
    }
    const unsigned lo = (unsigned)(unsigned short)f2bf(a0);
    const unsigned hi = (unsigned)(unsigned short)f2bf(a1);
    ((unsigned*)samp)[((size_t)q * 256 + h * HD_ + d0) >> 1] = lo | (hi << 16);
}

// ---------------------------------------------------------------------------
extern "C" void kernel_launch(void* const* d_in, const int* in_sizes, int n_in,
                              void* d_out, int out_size, void* d_ws, size_t ws_size,
                              hipStream_t stream)
{
    const float* query  = (const float*)d_in[0];
    const float* refpt  = (const float*)d_in[1];
    const float* value  = (const float*)d_in[2];
    const float* W_off  = (const float*)d_in[3];
    const float* b_off  = (const float*)d_in[4];
    const float* W_attn = (const float*)d_in[5];
    const float* b_attn = (const float*)d_in[6];
    const float* W_val  = (const float*)d_in[7];
    const float* b_val  = (const float*)d_in[8];
    const float* W_out  = (const float*)d_in[9];
    const float* b_out  = (const float*)d_in[10];
    float* out = (float*)d_out;

    char* ws = (char*)d_ws;
    short* vproj  = (short*)ws;                                   // 32 MiB bf16
    short* samp   = (short*)(ws + (size_t)32 * 1024 * 1024);      // 16 MiB bf16
    float* oa     = (float*)(ws + (size_t)48 * 1024 * 1024);      // 16 MiB f32 [32768][128]
    short* BtVal  = (short*)(ws + (size_t)64 * 1024 * 1024);      // 128 KiB
    short* BtOut  = BtVal + 256 * 256;                            // 128 KiB
    short* BtOA   = BtOut + 256 * 256;                            // 64 KiB
    float* biasOA = (float*)(BtOA + 128 * 256);                   // 512 B

    prep_kernel<<<640, 256, 0, stream>>>(W_val, W_out, W_off, W_attn,
                                         b_off, b_attn, BtVal, BtOut, BtOA, biasOA);

    // K1 (vproj) + K2a (off/attn) merged
    gemm_k1k2a<<<1280, 256, 0, stream>>>(value, BtVal, b_val, vproj,
                                         query, BtOA, biasOA, oa);

    // K2b: bilinear deformable sampling -> samp (bf16)
    sample_kernel<<<(B_ * NQ_) / 2, 256, 0, stream>>>(oa, refpt, vproj, samp);

    // K3: out = samp @ W_out + b_out, f32
    gemm_k3<<<512, 256, 0, stream>>>(samp, BtOut, b_out, out);
}

// Round 8
// 78.759 us; speedup vs baseline: 1.7216x; 1.0138x over previous
//
#include <hip/hip_runtime.h>
#include <cstddef>

#define B_   4
#define NQ_  8192
#define C_   256
#define H_   128
#define W_   128
#define HW_  (H_ * W_)
#define NH_  8
#define NP_  4
#define HD_  32

typedef __attribute__((ext_vector_type(8))) short s16x8;
typedef __attribute__((ext_vector_type(4))) float f32x4;

__device__ __forceinline__ short f2bf(float x) {
    unsigned u = __float_as_uint(x);
    unsigned r = (u + 0x7FFFu + ((u >> 16) & 1u)) >> 16;
    return (short)r;
}
__device__ __forceinline__ unsigned cvt_pk_bf16(float lo, float hi) {
    unsigned r;
    asm("v_cvt_pk_bf16_f32 %0, %1, %2" : "=v"(r) : "v"(lo), "v"(hi));
    return r;
}
__device__ __forceinline__ void gload_lds16(const void* g, void* l) {
    __builtin_amdgcn_global_load_lds(
        (const __attribute__((address_space(1))) void*)g,
        (__attribute__((address_space(3))) void*)l, 16, 0, 0);
}

// ---------------------------------------------------------------------------
// Prep: transposed bf16 weights Bt[n][k]. BtOA padded to 256 rows (rows
// 96..255 zero) so the merged kernel can use a uniform N=256 geometry.
// ---------------------------------------------------------------------------
__global__ void prep_kernel(const float* __restrict__ Wv, const float* __restrict__ Wo,
                            const float* __restrict__ Woff, const float* __restrict__ Wattn,
                            const float* __restrict__ boff, const float* __restrict__ battn,
                            short* __restrict__ BtVal, short* __restrict__ BtOut,
                            short* __restrict__ BtOA, float* __restrict__ biasOA)
{
    const int b = blockIdx.x, t = threadIdx.x;   // t = k index, 0..255
    if (b < 256) {
        const int n = b;
        BtVal[(size_t)n * 256 + t] = f2bf(Wv[(size_t)t * 256 + n]);
    } else if (b < 512) {
        const int n = b - 256;
        BtOut[(size_t)n * 256 + t] = f2bf(Wo[(size_t)t * 256 + n]);
    } else {
        const int n = b - 512;   // 0..255
        float v = (n < 64) ? Woff[(size_t)t * 64 + n]
                           : (n < 96 ? Wattn[(size_t)t * 32 + (n - 64)] : 0.f);
        BtOA[(size_t)n * 256 + t] = f2bf(v);
        if (t == 0) biasOA[n] = (n < 64) ? boff[n] : (n < 96 ? battn[n - 64] : 0.f);
    }
}

// ---------------------------------------------------------------------------
// Merged K1+K2a: 512 threads = 8 waves (2 wm x 4 wn of 64x64), tile 128 x 256.
// Full-N per block -> A panel read ONCE (halves A traffic vs split-N).
// 2-phase dbuf, ALL staging via global_load_lds (K3-proven: only vmcnt drain
// is inside __syncthreads). A fp32 staged with XOR-swizzled global source
// (involution, rule #21); fragments converted via v_cvt_pk_bf16_f32.
// LDS 64 KiB -> 2 blocks/CU = 4 waves/SIMD (K3's proven wave shape).
// blocks 0..511: vproj permute-store (omode 2). 512..767: K2a, oa store n<96.
// ---------------------------------------------------------------------------
__global__ __launch_bounds__(512, 4)
void gemm_k1k2a(const float* __restrict__ value, const short* __restrict__ BtVal,
                const float* __restrict__ b_val, short* __restrict__ vproj,
                const float* __restrict__ query, const short* __restrict__ BtOA,
                const float* __restrict__ biasOA, float* __restrict__ oa)
{
    __shared__ char  AsRaw[2 * 16384];   // fp32 A tile dbuf: 128 rows x 128 B
    __shared__ short Bs[2 * 8192];       // bf16 B tile dbuf: 256 rows x 64 B
    const int tid = threadIdx.x;
    const int l = tid & 63;
    const int w = tid >> 6;              // 0..7
    const int wm = w >> 2, wn = w & 3;
    const int bid = blockIdx.x;

    const float* Af;  const short* Bt;  const float* bias;
    int omode, m0;
    if (bid < 512) { Af = value; Bt = BtVal; bias = b_val;  omode = 2; m0 = bid * 128; }
    else           { Af = query; Bt = BtOA;  bias = biasOA; omode = 0; m0 = (bid - 512) * 128; }

    f32x4 acc[4][4];
#pragma unroll
    for (int i = 0; i < 4; ++i)
#pragma unroll
        for (int j = 0; j < 4; ++j) acc[i][j] = (f32x4)0.f;

    const int frag_r = l & 15;
    const int kslot  = (l >> 4) * 8;     // bf16 elems

#define STAGE_A(k0, buf)                                                      \
    _Pragma("unroll")                                                         \
    for (int r = 0; r < 2; ++r) {                                             \
        const int i = r * 512 + tid;                                          \
        const int row = i >> 3, s = i & 7;                                    \
        const int colf = (s * 4) ^ ((row & 7) << 2);   /* fp32 elems */       \
        gload_lds16(&Af[(size_t)(m0 + row) * 256 + (k0) + colf],              \
                    AsRaw + (buf) * 16384 + r * 8192 + w * 1024);             \
    }
#define STAGE_B(k0, buf)                                                      \
    _Pragma("unroll")                                                         \
    for (int r = 0; r < 2; ++r) {                                             \
        const int i = r * 512 + tid;                                          \
        const int row = i >> 2, cb = (i & 3) * 8;                             \
        gload_lds16(&Bt[(size_t)row * 256 + (k0) + cb],                       \
                    (char*)Bs + (buf) * 16384 + r * 8192 + w * 1024);         \
    }

    STAGE_B(0, 0);
    STAGE_A(0, 0);
    __syncthreads();

#pragma unroll
    for (int k = 0; k < 8; ++k) {
        const int cur = k & 1, nxt = cur ^ 1;
        if (k < 7) {
            STAGE_B((k + 1) * 32, nxt);
            STAGE_A((k + 1) * 32, nxt);
        }
        s16x8 a[4], b[4];
#pragma unroll
        for (int mf = 0; mf < 4; ++mf) {
            const int row = wm * 64 + mf * 16 + frag_r;
            const int g0 = (l >> 4) * 2;
            const char* base = AsRaw + cur * 16384 + row * 128;
            const float4 q0 = *(const float4*)(base + ((g0 * 16)       ^ ((row & 7) << 4)));
            const float4 q1 = *(const float4*)(base + (((g0 + 1) * 16) ^ ((row & 7) << 4)));
            union { unsigned u[4]; s16x8 v; } pk;
            pk.u[0] = cvt_pk_bf16(q0.x, q0.y);
            pk.u[1] = cvt_pk_bf16(q0.z, q0.w);
            pk.u[2] = cvt_pk_bf16(q1.x, q1.y);
            pk.u[3] = cvt_pk_bf16(q1.z, q1.w);
            a[mf] = pk.v;
        }
#pragma unroll
        for (int nf = 0; nf < 4; ++nf)
            b[nf] = *(const s16x8*)&Bs[cur * 8192 + (wn * 64 + nf * 16 + frag_r) * 32 + kslot];
#pragma unroll
        for (int mf = 0; mf < 4; ++mf)
#pragma unroll
            for (int nf = 0; nf < 4; ++nf)
                acc[mf][nf] = __builtin_amdgcn_mfma_f32_16x16x32_bf16(
                    a[mf], b[nf], acc[mf][nf], 0, 0, 0);
        if (k < 7) __syncthreads();
    }
#undef STAGE_A
#undef STAGE_B

    // ---- epilogue: C frag layout col=lane&15, row=(lane>>4)*4+reg ----
    const int col_local = wn * 64 + (l & 15);
    const int rbase = wm * 64 + (l >> 4) * 4;
#pragma unroll
    for (int nf = 0; nf < 4; ++nf) {
        const int n = col_local + nf * 16;
        if (omode == 0 && n >= 96) continue;
        const float bs = bias[n];
#pragma unroll
        for (int mf = 0; mf < 4; ++mf) {
            const f32x4 v = acc[mf][nf];
#pragma unroll
            for (int rr = 0; rr < 4; ++rr) {
                const int m = m0 + rbase + mf * 16 + rr;
                const float o = v[rr] + bs;
                if (omode == 0) {
                    oa[(size_t)m * 128 + n] = o;
                } else {
                    const int bb = m >> 14, pix = m & (HW_ - 1);
                    const int h = n >> 5, d = n & 31;
                    vproj[((size_t)(bb * NH_ + h) * HW_ + pix) * HD_ + d] = f2bf(o);
                }
            }
        }
    }
}

// ---------------------------------------------------------------------------
// K3: out = samp @ W_out + b_out. R6-proven roofline path (A bf16, 2-phase
// dbuf, 4 waves, 128x128 tile, all staging via global_load_lds).
// Grid MUST be 512: 256 m-chunks x 2 n-halves (1024 was the R7 OOB bug).
// ---------------------------------------------------------------------------
__global__ __launch_bounds__(256, 4)
void gemm_k3(const short* __restrict__ A16, const short* __restrict__ Bt,
             const float* __restrict__ bias, float* __restrict__ Cp)
{
    __shared__ char  AsRaw[2 * 8192];
    __shared__ short Bs[2 * 4096];
    const int tid = threadIdx.x;
    const int l = tid & 63;
    const int w = tid >> 6;
    const int wm = w >> 1, wn = w & 1;
    const int m0 = (blockIdx.x >> 1) * 128;
    const int n0 = (blockIdx.x & 1) * 128;

    f32x4 acc[4][4];
#pragma unroll
    for (int i = 0; i < 4; ++i)
#pragma unroll
        for (int j = 0; j < 4; ++j) acc[i][j] = (f32x4)0.f;

    const int frag_r = l & 15;
    const int kslot  = (l >> 4) * 8;

#define STAGE_B3(k0, buf)                                                     \
    _Pragma("unroll")                                                         \
    for (int r = 0; r < 2; ++r) {                                             \
        const int i = r * 256 + tid;                                          \
        gload_lds16(&Bt[(size_t)(n0 + (i >> 2)) * 256 + (k0) + (i & 3) * 8],  \
                    (char*)Bs + (buf) * 8192 + r * 4096 + w * 1024);          \
    }
#define STAGE_A3(k0, buf)                                                     \
    _Pragma("unroll")                                                         \
    for (int r = 0; r < 2; ++r) {                                             \
        const int i = r * 256 + tid;                                          \
        gload_lds16(&A16[(size_t)(m0 + (i >> 2)) * 256 + (k0) + (i & 3) * 8], \
                    AsRaw + (buf) * 8192 + r * 4096 + w * 1024);              \
    }

    STAGE_B3(0, 0);
    STAGE_A3(0, 0);
    __syncthreads();

#pragma unroll
    for (int k = 0; k < 8; ++k) {
        const int cur = k & 1, nxt = cur ^ 1;
        if (k < 7) {
            STAGE_B3((k + 1) * 32, nxt);
            STAGE_A3((k + 1) * 32, nxt);
        }
        s16x8 a[4], b[4];
#pragma unroll
        for (int mf = 0; mf < 4; ++mf)
            a[mf] = *(const s16x8*)(AsRaw + cur * 8192 + (wm * 64 + mf * 16 + frag_r) * 64 + kslot * 2);
#pragma unroll
        for (int nf = 0; nf < 4; ++nf)
            b[nf] = *(const s16x8*)&Bs[cur * 4096 + (wn * 64 + nf * 16 + frag_r) * 32 + kslot];
#pragma unroll
        for (int mf = 0; mf < 4; ++mf)
#pragma unroll
            for (int nf = 0; nf < 4; ++nf)
                acc[mf][nf] = __builtin_amdgcn_mfma_f32_16x16x32_bf16(
                    a[mf], b[nf], acc[mf][nf], 0, 0, 0);
        if (k < 7) __syncthreads();
    }
#undef STAGE_A3
#undef STAGE_B3

    const int col_local = wn * 64 + (l & 15);
    const int rbase = wm * 64 + (l >> 4) * 4;
#pragma unroll
    for (int nf = 0; nf < 4; ++nf) {
        const int n = n0 + col_local + nf * 16;
        const float bs = bias[n];
#pragma unroll
        for (int mf = 0; mf < 4; ++mf) {
            const f32x4 v = acc[mf][nf];
#pragma unroll
            for (int rr = 0; rr < 4; ++rr)
                Cp[(size_t)(m0 + rbase + mf * 16 + rr) * 256 + n] = v[rr] + bs;
        }
    }
}

// ---------------------------------------------------------------------------
// Sampling: block = 256 threads = 2 queries. Phase 1 (tid<64): softmax +
// corner indices + pre-multiplied weights -> LDS. Phase 2: (h, d-pair) gather.
// ---------------------------------------------------------------------------
__global__ __launch_bounds__(256)
void sample_kernel(const float* __restrict__ oa,    // [B*NQ, 128] (96 used)
                   const float* __restrict__ ref,   // [B*NQ, 2]
                   const short* __restrict__ vproj, // [B*NH, HW, HD] bf16
                   short* __restrict__ samp)        // [B*NQ, 256] bf16
{
    __shared__ int4   s_idx[2][32];
    __shared__ float4 s_w[2][32];
    const int tid = threadIdx.x;
    const int q0 = blockIdx.x * 2;

    if (tid < 64) {
        const int qq = tid >> 5;
        const int hp = tid & 31;
        const int h = hp >> 2, p = hp & 3;
        const int q = q0 + qq;
        const float logit = oa[(size_t)q * 128 + 64 + h * 4 + p];
        float mx = fmaxf(logit, __shfl_xor(logit, 1));
        mx = fmaxf(mx, __shfl_xor(mx, 2));
        float e = __expf(logit - mx);
        float s = e + __shfl_xor(e, 1);
        s += __shfl_xor(s, 2);
        const float aw = e / s;

        const float ox = oa[(size_t)q * 128 + h * 8 + p * 2 + 0] * (0.1f / (float)W_);
        const float oy = oa[(size_t)q * 128 + h * 8 + p * 2 + 1] * (0.1f / (float)H_);
        const float lx = fminf(fmaxf(ref[(size_t)q * 2 + 0] + ox, 0.f), 1.f);
        const float ly = fminf(fmaxf(ref[(size_t)q * 2 + 1] + oy, 0.f), 1.f);
        const float gx = fminf(fmaxf(lx * (float)W_ - 0.5f, 0.f), (float)(W_ - 1));
        const float gy = fminf(fmaxf(ly * (float)H_ - 0.5f, 0.f), (float)(H_ - 1));
        const float x0f = floorf(gx), y0f = floorf(gy);
        const float fx = gx - x0f, fy = gy - y0f;
        const int x0 = (int)x0f, y0 = (int)y0f;
        const int x1 = min(x0 + 1, W_ - 1), y1 = min(y0 + 1, H_ - 1);
        s_idx[qq][hp] = make_int4((y0 * W_ + x0) * HD_, (y0 * W_ + x1) * HD_,
                                  (y1 * W_ + x0) * HD_, (y1 * W_ + x1) * HD_);
        const float gx1 = 1.f - fx, gy1 = 1.f - fy;
        s_w[qq][hp] = make_float4(aw * gx1 * gy1, aw * fx * gy1,
                                  aw * gx1 * fy,  aw * fx * fy);
    }
    __syncthreads();

    const int qq = tid >> 7;
    const int t = tid & 127;
    const int h = t >> 4;
    const int d0 = (t & 15) * 2;
    const int q = q0 + qq;
    const int b = q >> 13;
    const short* vh = vproj + (size_t)(b * NH_ + h) * (HW_ * HD_) + d0;

    float a0 = 0.f, a1 = 0.f;
#pragma unroll
    for (int p = 0; p < 4; ++p) {
        const int4   ii = s_idx[qq][h * 4 + p];
        const float4 ww = s_w[qq][h * 4 + p];
        unsigned v;
        v = *(const unsigned*)&vh[ii.x];
        a0 = fmaf(ww.x, __uint_as_float(v << 16), a0);
        a1 = fmaf(ww.x, __uint_as_float(v & 0xFFFF0000u), a1);
        v = *(const unsigned*)&vh[ii.y];
        a0 = fmaf(ww.y, __uint_as_float(v << 16), a0);
        a1 = fmaf(ww.y, __uint_as_float(v & 0xFFFF0000u), a1);
        v = *(const unsigned*)&vh[ii.z];
        a0 = fmaf(ww.z, __uint_as_float(v << 16), a0);
        a1 = fmaf(ww.z, __uint_as_float(v & 0xFFFF0000u), a1);
        v = *(const unsigned*)&vh[ii.w];
        a0 = fmaf(ww.w, __uint_as_float(v << 16), a0);
        a1 = fmaf(ww.w, __uint_as_float(v & 0xFFFF0000u), a1);
    }
    const unsigned lo = (unsigned)(unsigned short)f2bf(a0);
    const unsigned hi = (unsigned)(unsigned short)f2bf(a1);
    ((unsigned*)samp)[((size_t)q * 256 + h * HD_ + d0) >> 1] = lo | (hi << 16);
}

// ---------------------------------------------------------------------------
extern "C" void kernel_launch(void* const* d_in, const int* in_sizes, int n_in,
                              void* d_out, int out_size, void* d_ws, size_t ws_size,
                              hipStream_t stream)
{
    const float* query  = (const float*)d_in[0];
    const float* refpt  = (const float*)d_in[1];
    const float* value  = (const float*)d_in[2];
    const float* W_off  = (const float*)d_in[3];
    const float* b_off  = (const float*)d_in[4];
    const float* W_attn = (const float*)d_in[5];
    const float* b_attn = (const float*)d_in[6];
    const float* W_val  = (const float*)d_in[7];
    const float* b_val  = (const float*)d_in[8];
    const float* W_out  = (const float*)d_in[9];
    const float* b_out  = (const float*)d_in[10];
    float* out = (float*)d_out;

    char* ws = (char*)d_ws;
    short* vproj  = (short*)ws;                                   // 32 MiB bf16
    short* samp   = (short*)(ws + (size_t)32 * 1024 * 1024);      // 16 MiB bf16
    float* oa     = (float*)(ws + (size_t)48 * 1024 * 1024);      // 16 MiB f32 [32768][128]
    short* BtVal  = (short*)(ws + (size_t)64 * 1024 * 1024);      // 128 KiB
    short* BtOut  = BtVal + 256 * 256;                            // 128 KiB
    short* BtOA   = BtOut + 256 * 256;                            // 128 KiB (256 rows)
    float* biasOA = (float*)(BtOA + 256 * 256);                   // 1 KiB

    prep_kernel<<<768, 256, 0, stream>>>(W_val, W_out, W_off, W_attn,
                                         b_off, b_attn, BtVal, BtOut, BtOA, biasOA);

    // K1 (vproj, blocks 0..511, full N=256) + K2a (blocks 512..767)
    gemm_k1k2a<<<768, 512, 0, stream>>>(value, BtVal, b_val, vproj,
                                        query, BtOA, biasOA, oa);

    // K2b: bilinear deformable sampling -> samp (bf16)
    sample_kernel<<<(B_ * NQ_) / 2, 256, 0, stream>>>(oa, refpt, vproj, samp);

    // K3: out = samp @ W_out + b_out, f32
    gemm_k3<<<512, 256, 0, stream>>>(samp, BtOut, b_out, out);
}